// Round 1
// baseline (248.070 us; speedup 1.0000x reference)
//
#include <hip/hip_runtime.h>
#include <hip/hip_bf16.h>
#include <math.h>

typedef __bf16 bf16;
typedef __bf16 bf16x8 __attribute__((ext_vector_type(8)));
typedef float  f32x4  __attribute__((ext_vector_type(4)));

#define MFMA16(a, b, c) __builtin_amdgcn_mfma_f32_16x16x32_bf16((a), (b), (c), 0, 0, 0)

constexpr int B_ = 8, C_ = 80, T_ = 2048, D_ = 256;
constexpr float SCALE_INV = 1.0f / 16.0f;  // 1/sqrt(256)

// ---------------------------------------------------------------------------
// Kernel 1: projection. K = xt @ Wk^T + bk, Q = xt @ Wq^T + bq (bf16 out),
// plus bf16 conversion of x (kept in [B][C][T] layout = V^T for the PV step).
// Bias folded in by padding C 80->96 with xt[:,80]=1, W[:,80]=bias.
// Block: 256 threads (4 waves), covers 32 t-rows x all 256 d, grid (T/32, B).
// ---------------------------------------------------------------------------
__global__ __launch_bounds__(256) void proj_kernel(
    const float* __restrict__ x,   // [B][C][T]
    const float* __restrict__ Wk,  // [D][C]
    const float* __restrict__ bk,  // [D]
    const float* __restrict__ Wq,  // [D][C]
    const float* __restrict__ bq,  // [D]
    bf16* __restrict__ Kb,         // [B][T][D]
    bf16* __restrict__ Qb,         // [B][T][D]
    bf16* __restrict__ xbf)        // [B][C][T]
{
  const int t0   = blockIdx.x * 32;
  const int b    = blockIdx.y;
  const int tid  = threadIdx.x;
  const int w    = tid >> 6;
  const int lane = tid & 63;
  const int h    = lane >> 4;   // 0..3
  const int lr   = lane & 15;   // 0..15

  const float* xb = x + (size_t)b * C_ * T_;

  // --- part 1: bf16-convert this block's x slice [all c][t0..t0+31] ---
  {
    bf16* ob = xbf + (size_t)b * C_ * T_;
    #pragma unroll
    for (int q = 0; q < 10; ++q) {
      int idx = q * 256 + tid;        // 0..2559
      int c = idx >> 5, tt = idx & 31;
      ob[c * T_ + t0 + tt] = (bf16)xb[c * T_ + t0 + tt];
    }
  }

  // --- A-fragments: xt rows t0..t0+31 (2 ib blocks), c padded to 96 ---
  bf16x8 afrag[2][3];
  #pragma unroll
  for (int ib = 0; ib < 2; ++ib) {
    int t = t0 + ib * 16 + lr;
    #pragma unroll
    for (int ks = 0; ks < 3; ++ks) {
      bf16x8 v;
      #pragma unroll
      for (int e = 0; e < 8; ++e) {
        int c = ks * 32 + h * 8 + e;
        float val;
        if (c < 80)       val = xb[c * T_ + t];
        else if (c == 80) val = 1.0f;
        else              val = 0.0f;
        v[e] = (bf16)val;
      }
      afrag[ib][ks] = v;
    }
  }

  // --- per matrix: B-frags from W rows, MFMA, store bf16 ---
  const int nb0 = w * 4;  // this wave's 4 n-blocks (d = (nb0+nb)*16 + lr)
  #pragma unroll
  for (int mat = 0; mat < 2; ++mat) {
    const float* W    = mat ? Wq : Wk;
    const float* bias = mat ? bq : bk;
    bf16* outp        = mat ? Qb : Kb;

    f32x4 acc[2][4];
    #pragma unroll
    for (int ib = 0; ib < 2; ++ib)
      #pragma unroll
      for (int nb = 0; nb < 4; ++nb)
        acc[ib][nb] = f32x4{0.f, 0.f, 0.f, 0.f};

    #pragma unroll
    for (int nb = 0; nb < 4; ++nb) {
      int d = (nb0 + nb) * 16 + lr;
      #pragma unroll
      for (int ks = 0; ks < 3; ++ks) {
        bf16x8 bv;
        #pragma unroll
        for (int e = 0; e < 8; ++e) {
          int c = ks * 32 + h * 8 + e;
          float val;
          if (c < 80)       val = W[d * C_ + c];
          else if (c == 80) val = bias[d];
          else              val = 0.0f;
          bv[e] = (bf16)val;
        }
        #pragma unroll
        for (int ib = 0; ib < 2; ++ib)
          acc[ib][nb] = MFMA16(afrag[ib][ks], bv, acc[ib][nb]);
      }
    }

    #pragma unroll
    for (int ib = 0; ib < 2; ++ib)
      #pragma unroll
      for (int nb = 0; nb < 4; ++nb) {
        int d = (nb0 + nb) * 16 + lr;
        #pragma unroll
        for (int r = 0; r < 4; ++r) {
          int t = t0 + ib * 16 + h * 4 + r;
          outp[(size_t)(b * T_ + t) * D_ + d] = (bf16)acc[ib][nb][r];
        }
      }
  }
}

// ---------------------------------------------------------------------------
// Kernel 2: flash attention. Rows = K-rows (i), cols = Q-rows (j), V = xt.
// Block: 4 waves x 16 i-rows = 64 rows; iterate 32 j-tiles of 64.
// Q tile reg-staged into XOR-swizzled LDS (double buffered).
// P (scores->probs) round-trips through a private per-wave swizzled buffer
// to convert MFMA C/D layout -> A layout. V frags read straight from xbf
// ([C][T] layout => contiguous 8-elem reads), L2-resident.
// ---------------------------------------------------------------------------
__global__ __launch_bounds__(256) void attn_kernel(
    const bf16* __restrict__ Kb,   // [B][T][D]
    const bf16* __restrict__ Qb,   // [B][T][D]
    const bf16* __restrict__ xbf,  // [B][C][T]
    float* __restrict__ out)       // [B][C][T]
{
  constexpr int BM = 64, BN = 64, NT = T_ / BN;  // NT = 32
  __shared__ bf16 qlds[2][BN * D_];    // 2 x 32 KB
  __shared__ bf16 plds[4][16 * BN];    // per-wave P buffer, 4 x 2 KB

  const int i0   = blockIdx.x * BM;
  const int b    = blockIdx.y;
  const int tid  = threadIdx.x;
  const int w    = tid >> 6;
  const int lane = tid & 63;
  const int h    = lane >> 4;
  const int lr   = lane & 15;

  const bf16* Kbase = Kb + (size_t)(b * T_) * D_;
  const bf16* Qbase = Qb + (size_t)(b * T_) * D_;

  // K A-frags for this wave's 16 rows: K[i0+16w+lr][8h+e+32ks]
  bf16x8 kfrag[8];
  {
    const bf16* kp = Kbase + (size_t)(i0 + w * 16 + lr) * D_ + h * 8;
    #pragma unroll
    for (int ks = 0; ks < 8; ++ks)
      kfrag[ks] = *reinterpret_cast<const bf16x8*>(kp + ks * 32);
  }

  f32x4 oacc[5];
  #pragma unroll
  for (int nb = 0; nb < 5; ++nb) oacc[nb] = f32x4{0.f, 0.f, 0.f, 0.f};
  float m_run[4], l_run[4];
  #pragma unroll
  for (int r = 0; r < 4; ++r) { m_run[r] = -INFINITY; l_run[r] = 0.f; }

  uint4 stg[8];  // staging regs: 8 x 16 B per thread = 32 KB per block

  auto load_stage = [&](int jt) {
    const uint4* src = reinterpret_cast<const uint4*>(Qbase + (size_t)jt * BN * D_);
    #pragma unroll
    for (int q = 0; q < 8; ++q) {
      int f = tid + 256 * q;          // flat 16B-chunk id: j = f/32, c8 = f%32
      stg[q] = src[f];
    }
  };
  auto write_stage = [&](int buf) {
    #pragma unroll
    for (int q = 0; q < 8; ++q) {
      int f = tid + 256 * q;
      int j = f >> 5, c8 = f & 31;
      *reinterpret_cast<uint4*>(&qlds[buf][(j << 8) + ((c8 ^ (j & 7)) << 3)]) = stg[q];
    }
  };

  load_stage(0);
  write_stage(0);
  __syncthreads();

  for (int jt = 0; jt < NT; ++jt) {
    const int cur = jt & 1;
    if (jt + 1 < NT) load_stage(jt + 1);  // async prefetch into regs

    // --- S = K Q^T (this wave: 16 i x 64 j) ---
    f32x4 s[4];
    #pragma unroll
    for (int jb = 0; jb < 4; ++jb) s[jb] = f32x4{0.f, 0.f, 0.f, 0.f};
    #pragma unroll
    for (int jb = 0; jb < 4; ++jb) {
      const int j = lr + jb * 16;
      const int swz = (j & 7);
      #pragma unroll
      for (int ks = 0; ks < 8; ++ks) {
        bf16x8 qf = *reinterpret_cast<const bf16x8*>(
            &qlds[cur][(j << 8) + (((h + 4 * ks) ^ swz) << 3)]);
        s[jb] = MFMA16(kfrag[ks], qf, s[jb]);
      }
    }

    // --- online softmax over j; lane holds rows i=4h+r, cols j=lr+16jb ---
    #pragma unroll
    for (int jb = 0; jb < 4; ++jb)
      #pragma unroll
      for (int r = 0; r < 4; ++r) s[jb][r] *= SCALE_INV;

    float p[4][4];   // [jb][r]
    float alpha[4];
    #pragma unroll
    for (int r = 0; r < 4; ++r) {
      float mx = fmaxf(fmaxf(s[0][r], s[1][r]), fmaxf(s[2][r], s[3][r]));
      mx = fmaxf(mx, __shfl_xor(mx, 1));
      mx = fmaxf(mx, __shfl_xor(mx, 2));
      mx = fmaxf(mx, __shfl_xor(mx, 4));
      mx = fmaxf(mx, __shfl_xor(mx, 8));
      float mnew = fmaxf(m_run[r], mx);
      alpha[r]  = __expf(m_run[r] - mnew);   // first tile: exp(-inf)=0
      m_run[r]  = mnew;
      float rs = 0.f;
      #pragma unroll
      for (int jb = 0; jb < 4; ++jb) {
        p[jb][r] = __expf(s[jb][r] - mnew);
        rs += p[jb][r];
      }
      rs += __shfl_xor(rs, 1);
      rs += __shfl_xor(rs, 2);
      rs += __shfl_xor(rs, 4);
      rs += __shfl_xor(rs, 8);
      l_run[r] = l_run[r] * alpha[r] + rs;
    }

    #pragma unroll
    for (int nb = 0; nb < 5; ++nb)
      #pragma unroll
      for (int r = 0; r < 4; ++r) oacc[nb][r] *= alpha[r];

    // --- P -> per-wave LDS (bf16, swizzled by (row&7) on 16B chunks) ---
    #pragma unroll
    for (int jb = 0; jb < 4; ++jb)
      #pragma unroll
      for (int r = 0; r < 4; ++r) {
        int row = h * 4 + r;
        int col = lr + jb * 16;
        plds[w][row * 64 + (((col >> 3) ^ (row & 7)) << 3) + (col & 7)] =
            (bf16)p[jb][r];
      }

    // --- read P as A-frags, V frags from global, PV MFMA ---
    bf16x8 pa[2];
    #pragma unroll
    for (int ks = 0; ks < 2; ++ks) {
      pa[ks] = *reinterpret_cast<const bf16x8*>(
          &plds[w][lr * 64 + (((h + 4 * ks) ^ (lr & 7)) << 3)]);
    }
    const bf16* vbase = xbf + (size_t)b * C_ * T_ + jt * BN;
    #pragma unroll
    for (int nb = 0; nb < 5; ++nb) {
      const int c = lr + nb * 16;
      #pragma unroll
      for (int ks = 0; ks < 2; ++ks) {
        bf16x8 vf = *reinterpret_cast<const bf16x8*>(
            &vbase[(size_t)c * T_ + h * 8 + ks * 32]);
        oacc[nb] = MFMA16(pa[ks], vf, oacc[nb]);
      }
    }

    __syncthreads();                        // all waves done reading qlds[cur^1]
    if (jt + 1 < NT) write_stage((jt + 1) & 1);
    __syncthreads();                        // next tile visible to all waves
  }

  // --- epilogue: out[b][c][i] = O / l ---
  float inv[4];
  #pragma unroll
  for (int r = 0; r < 4; ++r) inv[r] = 1.0f / l_run[r];
  float* ob = out + (size_t)b * C_ * T_;
  #pragma unroll
  for (int nb = 0; nb < 5; ++nb) {
    const int c = lr + nb * 16;
    #pragma unroll
    for (int r = 0; r < 4; ++r) {
      const int i = i0 + w * 16 + h * 4 + r;
      ob[(size_t)c * T_ + i] = oacc[nb][r] * inv[r];
    }
  }
}

// ---------------------------------------------------------------------------
extern "C" void kernel_launch(void* const* d_in, const int* in_sizes, int n_in,
                              void* d_out, int out_size, void* d_ws, size_t ws_size,
                              hipStream_t stream) {
  (void)in_sizes; (void)n_in; (void)out_size; (void)ws_size;
  const float* x  = (const float*)d_in[0];
  const float* Wk = (const float*)d_in[1];
  const float* bk = (const float*)d_in[2];
  const float* Wq = (const float*)d_in[3];
  const float* bq = (const float*)d_in[4];
  float* out = (float*)d_out;

  char* ws = (char*)d_ws;
  bf16* Kb  = (bf16*)(ws);                      // 8 MB
  bf16* Qb  = (bf16*)(ws + (size_t)8 * 1024 * 1024);   // 8 MB
  bf16* xbf = (bf16*)(ws + (size_t)16 * 1024 * 1024);  // 2.5 MB

  dim3 blk(256);
  dim3 g1(T_ / 32, B_);
  proj_kernel<<<g1, blk, 0, stream>>>(x, Wk, bk, Wq, bq, Kb, Qb, xbf);
  dim3 g2(T_ / 64, B_);
  attn_kernel<<<g2, blk, 0, stream>>>(Kb, Qb, xbf, out);
}

// Round 2
// 156.230 us; speedup vs baseline: 1.5879x; 1.5879x over previous
//
#include <hip/hip_runtime.h>
#include <hip/hip_bf16.h>
#include <math.h>

typedef __bf16 bf16;
typedef __bf16 bf16x8 __attribute__((ext_vector_type(8)));
typedef float  f32x4  __attribute__((ext_vector_type(4)));

#define MFMA16(a, b, c) __builtin_amdgcn_mfma_f32_16x16x32_bf16((a), (b), (c), 0, 0, 0)

constexpr int B_ = 8, C_ = 80, T_ = 2048, D_ = 256;
constexpr int NS = 4;                       // j-splits (flash-decode style)
constexpr float SCALE_INV = 1.0f / 16.0f;   // 1/sqrt(256)

// ---------------------------------------------------------------------------
// Kernel 1: projection. K = xt @ Wk^T + bk, Q = xt @ Wq^T + bq (bf16 out),
// plus bf16 conversion of x (kept in [B][C][T] layout = V^T for the PV step).
// Bias folded in by padding C 80->96 with xt[:,80]=1, W[:,80]=bias.
// ---------------------------------------------------------------------------
__global__ __launch_bounds__(256) void proj_kernel(
    const float* __restrict__ x,   // [B][C][T]
    const float* __restrict__ Wk,  // [D][C]
    const float* __restrict__ bk,  // [D]
    const float* __restrict__ Wq,  // [D][C]
    const float* __restrict__ bq,  // [D]
    bf16* __restrict__ Kb,         // [B][T][D]
    bf16* __restrict__ Qb,         // [B][T][D]
    bf16* __restrict__ xbf)        // [B][C][T]
{
  const int t0   = blockIdx.x * 32;
  const int b    = blockIdx.y;
  const int tid  = threadIdx.x;
  const int w    = tid >> 6;
  const int lane = tid & 63;
  const int h    = lane >> 4;   // 0..3
  const int lr   = lane & 15;   // 0..15

  const float* xb = x + (size_t)b * C_ * T_;

  // bf16-convert this block's x slice
  {
    bf16* ob = xbf + (size_t)b * C_ * T_;
    #pragma unroll
    for (int q = 0; q < 10; ++q) {
      int idx = q * 256 + tid;
      int c = idx >> 5, tt = idx & 31;
      ob[c * T_ + t0 + tt] = (bf16)xb[c * T_ + t0 + tt];
    }
  }

  // A-fragments: xt rows t0..t0+31, c padded to 96
  bf16x8 afrag[2][3];
  #pragma unroll
  for (int ib = 0; ib < 2; ++ib) {
    int t = t0 + ib * 16 + lr;
    #pragma unroll
    for (int ks = 0; ks < 3; ++ks) {
      bf16x8 v;
      #pragma unroll
      for (int e = 0; e < 8; ++e) {
        int c = ks * 32 + h * 8 + e;
        float val;
        if (c < 80)       val = xb[c * T_ + t];
        else if (c == 80) val = 1.0f;
        else              val = 0.0f;
        v[e] = (bf16)val;
      }
      afrag[ib][ks] = v;
    }
  }

  const int nb0 = w * 4;
  #pragma unroll
  for (int mat = 0; mat < 2; ++mat) {
    const float* W    = mat ? Wq : Wk;
    const float* bias = mat ? bq : bk;
    bf16* outp        = mat ? Qb : Kb;

    f32x4 acc[2][4];
    #pragma unroll
    for (int ib = 0; ib < 2; ++ib)
      #pragma unroll
      for (int nb = 0; nb < 4; ++nb)
        acc[ib][nb] = f32x4{0.f, 0.f, 0.f, 0.f};

    #pragma unroll
    for (int nb = 0; nb < 4; ++nb) {
      int d = (nb0 + nb) * 16 + lr;
      #pragma unroll
      for (int ks = 0; ks < 3; ++ks) {
        bf16x8 bv;
        #pragma unroll
        for (int e = 0; e < 8; ++e) {
          int c = ks * 32 + h * 8 + e;
          float val;
          if (c < 80)       val = W[d * C_ + c];
          else if (c == 80) val = bias[d];
          else              val = 0.0f;
          bv[e] = (bf16)val;
        }
        #pragma unroll
        for (int ib = 0; ib < 2; ++ib)
          acc[ib][nb] = MFMA16(afrag[ib][ks], bv, acc[ib][nb]);
      }
    }

    #pragma unroll
    for (int ib = 0; ib < 2; ++ib)
      #pragma unroll
      for (int nb = 0; nb < 4; ++nb) {
        int d = (nb0 + nb) * 16 + lr;
        #pragma unroll
        for (int r = 0; r < 4; ++r) {
          int t = t0 + ib * 16 + h * 4 + r;
          outp[(size_t)(b * T_ + t) * D_ + d] = (bf16)acc[ib][nb][r];
        }
      }
  }
}

// ---------------------------------------------------------------------------
// Kernel 2: flash attention with j-splits. Block = 4 waves x 16 i-rows;
// blockIdx.y = split s covers j in [s*512, (s+1)*512) = 8 tiles of BN=64.
// Writes unnormalized O_s + (m_s, l_s) partials. Single-buffered Q LDS
// (reg prefetch covers latency) -> 40KB LDS -> 4 blocks/CU.
// ---------------------------------------------------------------------------
__global__ __launch_bounds__(256, 4) void attn_kernel(
    const bf16* __restrict__ Kb,   // [B][T][D]
    const bf16* __restrict__ Qb,   // [B][T][D]
    const bf16* __restrict__ xbf,  // [B][C][T]
    float* __restrict__ Opart,     // [NS][B][C][T]
    float* __restrict__ mpart,     // [NS][B][T]
    float* __restrict__ lpart)     // [NS][B][T]
{
  constexpr int BM = 64, BN = 64, NT = T_ / BN;  // NT = 32
  constexpr int JT_PER = NT / NS;                // 8
  __shared__ bf16 qlds[BN * D_];       // 32 KB
  __shared__ bf16 plds[4][16 * BN];    // 8 KB

  const int i0   = blockIdx.x * BM;
  const int s    = blockIdx.y;
  const int b    = blockIdx.z;
  const int tid  = threadIdx.x;
  const int w    = tid >> 6;
  const int lane = tid & 63;
  const int h    = lane >> 4;
  const int lr   = lane & 15;

  const bf16* Kbase = Kb + (size_t)(b * T_) * D_;
  const bf16* Qbase = Qb + (size_t)(b * T_) * D_;

  // K A-frags for this wave's 16 rows
  bf16x8 kfrag[8];
  {
    const bf16* kp = Kbase + (size_t)(i0 + w * 16 + lr) * D_ + h * 8;
    #pragma unroll
    for (int ks = 0; ks < 8; ++ks)
      kfrag[ks] = *reinterpret_cast<const bf16x8*>(kp + ks * 32);
  }

  f32x4 oacc[5];
  #pragma unroll
  for (int nb = 0; nb < 5; ++nb) oacc[nb] = f32x4{0.f, 0.f, 0.f, 0.f};
  float m_run[4], l_run[4];
  #pragma unroll
  for (int r = 0; r < 4; ++r) { m_run[r] = -INFINITY; l_run[r] = 0.f; }

  uint4 stg[8];

  auto load_stage = [&](int jt) {
    const uint4* src = reinterpret_cast<const uint4*>(Qbase + (size_t)jt * BN * D_);
    #pragma unroll
    for (int q = 0; q < 8; ++q) stg[q] = src[tid + 256 * q];
  };
  auto write_stage = [&]() {
    #pragma unroll
    for (int q = 0; q < 8; ++q) {
      int f = tid + 256 * q;
      int j = f >> 5, c8 = f & 31;
      *reinterpret_cast<uint4*>(&qlds[(j << 8) + ((c8 ^ (j & 7)) << 3)]) = stg[q];
    }
  };

  const int jt0 = s * JT_PER, jt_end = jt0 + JT_PER;

  load_stage(jt0);
  write_stage();
  __syncthreads();

  for (int jt = jt0; jt < jt_end; ++jt) {
    if (jt + 1 < jt_end) load_stage(jt + 1);  // prefetch into regs

    // --- S = K Q^T (this wave: 16 i x 64 j) ---
    f32x4 sacc[4];
    #pragma unroll
    for (int jb = 0; jb < 4; ++jb) sacc[jb] = f32x4{0.f, 0.f, 0.f, 0.f};
    #pragma unroll
    for (int jb = 0; jb < 4; ++jb) {
      const int j = lr + jb * 16;
      const int swz = (j & 7);
      #pragma unroll
      for (int ks = 0; ks < 8; ++ks) {
        bf16x8 qf = *reinterpret_cast<const bf16x8*>(
            &qlds[(j << 8) + (((h + 4 * ks) ^ swz) << 3)]);
        sacc[jb] = MFMA16(kfrag[ks], qf, sacc[jb]);
      }
    }

    // --- online softmax over this split's j ---
    #pragma unroll
    for (int jb = 0; jb < 4; ++jb)
      #pragma unroll
      for (int r = 0; r < 4; ++r) sacc[jb][r] *= SCALE_INV;

    float p[4][4];
    float alpha[4];
    #pragma unroll
    for (int r = 0; r < 4; ++r) {
      float mx = fmaxf(fmaxf(sacc[0][r], sacc[1][r]), fmaxf(sacc[2][r], sacc[3][r]));
      mx = fmaxf(mx, __shfl_xor(mx, 1));
      mx = fmaxf(mx, __shfl_xor(mx, 2));
      mx = fmaxf(mx, __shfl_xor(mx, 4));
      mx = fmaxf(mx, __shfl_xor(mx, 8));
      float mnew = fmaxf(m_run[r], mx);
      alpha[r]  = __expf(m_run[r] - mnew);
      m_run[r]  = mnew;
      float rs = 0.f;
      #pragma unroll
      for (int jb = 0; jb < 4; ++jb) {
        p[jb][r] = __expf(sacc[jb][r] - mnew);
        rs += p[jb][r];
      }
      rs += __shfl_xor(rs, 1);
      rs += __shfl_xor(rs, 2);
      rs += __shfl_xor(rs, 4);
      rs += __shfl_xor(rs, 8);
      l_run[r] = l_run[r] * alpha[r] + rs;
    }

    #pragma unroll
    for (int nb = 0; nb < 5; ++nb)
      #pragma unroll
      for (int r = 0; r < 4; ++r) oacc[nb][r] *= alpha[r];

    // --- P -> per-wave LDS (bf16, swizzled) ---
    #pragma unroll
    for (int jb = 0; jb < 4; ++jb)
      #pragma unroll
      for (int r = 0; r < 4; ++r) {
        int row = h * 4 + r;
        int col = lr + jb * 16;
        plds[w][row * 64 + (((col >> 3) ^ (row & 7)) << 3) + (col & 7)] =
            (bf16)p[jb][r];
      }

    // --- read P as A-frags, V frags from global (L2), PV MFMA ---
    bf16x8 pa[2];
    #pragma unroll
    for (int ks = 0; ks < 2; ++ks) {
      pa[ks] = *reinterpret_cast<const bf16x8*>(
          &plds[w][lr * 64 + (((h + 4 * ks) ^ (lr & 7)) << 3)]);
    }
    const bf16* vbase = xbf + (size_t)b * C_ * T_ + jt * BN;
    #pragma unroll
    for (int nb = 0; nb < 5; ++nb) {
      const int c = lr + nb * 16;
      #pragma unroll
      for (int ks = 0; ks < 2; ++ks) {
        bf16x8 vf = *reinterpret_cast<const bf16x8*>(
            &vbase[(size_t)c * T_ + h * 8 + ks * 32]);
        oacc[nb] = MFMA16(pa[ks], vf, oacc[nb]);
      }
    }

    __syncthreads();                  // all waves done reading qlds
    if (jt + 1 < jt_end) write_stage();
    __syncthreads();                  // next tile visible
  }

  // --- epilogue: unnormalized partials ---
  float* ob = Opart + (size_t)(s * B_ + b) * C_ * T_;
  #pragma unroll
  for (int nb = 0; nb < 5; ++nb) {
    const int c = lr + nb * 16;
    #pragma unroll
    for (int r = 0; r < 4; ++r) {
      const int i = i0 + w * 16 + h * 4 + r;
      ob[(size_t)c * T_ + i] = oacc[nb][r];
    }
  }
  if (lr == 0) {
    #pragma unroll
    for (int r = 0; r < 4; ++r) {
      const int i = i0 + w * 16 + h * 4 + r;
      mpart[(size_t)(s * B_ + b) * T_ + i] = m_run[r];
      lpart[(size_t)(s * B_ + b) * T_ + i] = l_run[r];
    }
  }
}

// ---------------------------------------------------------------------------
// Kernel 3: merge splits. out[b][c][t] = sum_s O_s e^{m_s-m*} / sum_s l_s e^{m_s-m*}
// Block: 256 threads = 4 waves; wave w handles c-chunk [20w, 20w+20);
// lane owns t = blockIdx.x*64 + lane. Grid (T/64, B).
// ---------------------------------------------------------------------------
__global__ __launch_bounds__(256) void merge_kernel(
    const float* __restrict__ Opart,  // [NS][B][C][T]
    const float* __restrict__ mpart,  // [NS][B][T]
    const float* __restrict__ lpart,  // [NS][B][T]
    float* __restrict__ out)          // [B][C][T]
{
  const int b    = blockIdx.y;
  const int tid  = threadIdx.x;
  const int w    = tid >> 6;
  const int lane = tid & 63;
  const int t    = blockIdx.x * 64 + lane;

  float m[NS];
  float mmax = -INFINITY;
  #pragma unroll
  for (int s2 = 0; s2 < NS; ++s2) {
    m[s2] = mpart[(size_t)(s2 * B_ + b) * T_ + t];
    mmax = fmaxf(mmax, m[s2]);
  }
  float e[NS];
  float lsum = 0.f;
  #pragma unroll
  for (int s2 = 0; s2 < NS; ++s2) {
    e[s2] = __expf(m[s2] - mmax);
    lsum += e[s2] * lpart[(size_t)(s2 * B_ + b) * T_ + t];
  }
  const float inv = 1.0f / lsum;

  const int c0 = w * 20;
  for (int c = c0; c < c0 + 20; ++c) {
    float acc = 0.f;
    #pragma unroll
    for (int s2 = 0; s2 < NS; ++s2)
      acc += Opart[((size_t)(s2 * B_ + b) * C_ + c) * T_ + t] * e[s2];
    out[((size_t)b * C_ + c) * T_ + t] = acc * inv;
  }
}

// ---------------------------------------------------------------------------
extern "C" void kernel_launch(void* const* d_in, const int* in_sizes, int n_in,
                              void* d_out, int out_size, void* d_ws, size_t ws_size,
                              hipStream_t stream) {
  (void)in_sizes; (void)n_in; (void)out_size; (void)ws_size;
  const float* x  = (const float*)d_in[0];
  const float* Wk = (const float*)d_in[1];
  const float* bk = (const float*)d_in[2];
  const float* Wq = (const float*)d_in[3];
  const float* bq = (const float*)d_in[4];
  float* out = (float*)d_out;

  char* ws = (char*)d_ws;
  const size_t MB = 1024 * 1024;
  bf16*  Kb    = (bf16*)(ws);                 // 8 MB
  bf16*  Qb    = (bf16*)(ws + 8 * MB);        // 8 MB
  bf16*  xbf   = (bf16*)(ws + 16 * MB);       // 2.625 MB
  float* Opart = (float*)(ws + 19 * MB);      // NS*8*80*2048*4 = 20.97 MB
  float* mpart = (float*)(ws + 41 * MB);      // 256 KB
  float* lpart = (float*)(ws + 42 * MB);      // 256 KB

  dim3 blk(256);
  dim3 g1(T_ / 32, B_);
  proj_kernel<<<g1, blk, 0, stream>>>(x, Wk, bk, Wq, bq, Kb, Qb, xbf);
  dim3 g2(T_ / 64, NS, B_);
  attn_kernel<<<g2, blk, 0, stream>>>(Kb, Qb, xbf, Opart, mpart, lpart);
  dim3 g3(T_ / 64, B_);
  merge_kernel<<<g3, blk, 0, stream>>>(Opart, mpart, lpart, out);
}

// Round 3
// 139.173 us; speedup vs baseline: 1.7825x; 1.1226x over previous
//
#include <hip/hip_runtime.h>
#include <hip/hip_bf16.h>
#include <math.h>

typedef __bf16 bf16;
typedef __bf16 bf16x8 __attribute__((ext_vector_type(8)));
typedef float  f32x4  __attribute__((ext_vector_type(4)));

#define MFMA16(a, b, c) __builtin_amdgcn_mfma_f32_16x16x32_bf16((a), (b), (c), 0, 0, 0)

constexpr int B_ = 8, C_ = 80, T_ = 2048, D_ = 256;
constexpr int NS = 4;                       // j-splits (flash-decode style)
constexpr float SCALE_INV = 1.0f / 16.0f;   // 1/sqrt(256)

// ---------------------------------------------------------------------------
// Kernel 1: projection. K = xt @ Wk^T + bk, Q = xt @ Wq^T + bq (bf16 out),
// plus bf16 conversion of x (kept in [B][C][T] layout = V^T for the PV step).
// Bias folded in by padding C 80->96 with xt[:,80]=1, W[:,80]=bias.
// ---------------------------------------------------------------------------
__global__ __launch_bounds__(256) void proj_kernel(
    const float* __restrict__ x,   // [B][C][T]
    const float* __restrict__ Wk,  // [D][C]
    const float* __restrict__ bk,  // [D]
    const float* __restrict__ Wq,  // [D][C]
    const float* __restrict__ bq,  // [D]
    bf16* __restrict__ Kb,         // [B][T][D]
    bf16* __restrict__ Qb,         // [B][T][D]
    bf16* __restrict__ xbf)        // [B][C][T]
{
  const int t0   = blockIdx.x * 32;
  const int b    = blockIdx.y;
  const int tid  = threadIdx.x;
  const int w    = tid >> 6;
  const int lane = tid & 63;
  const int h    = lane >> 4;   // 0..3
  const int lr   = lane & 15;   // 0..15

  const float* xb = x + (size_t)b * C_ * T_;

  // bf16-convert this block's x slice
  {
    bf16* ob = xbf + (size_t)b * C_ * T_;
    #pragma unroll
    for (int q = 0; q < 10; ++q) {
      int idx = q * 256 + tid;
      int c = idx >> 5, tt = idx & 31;
      ob[c * T_ + t0 + tt] = (bf16)xb[c * T_ + t0 + tt];
    }
  }

  // A-fragments: xt rows t0..t0+31, c padded to 96
  bf16x8 afrag[2][3];
  #pragma unroll
  for (int ib = 0; ib < 2; ++ib) {
    int t = t0 + ib * 16 + lr;
    #pragma unroll
    for (int ks = 0; ks < 3; ++ks) {
      bf16x8 v;
      #pragma unroll
      for (int e = 0; e < 8; ++e) {
        int c = ks * 32 + h * 8 + e;
        float val;
        if (c < 80)       val = xb[c * T_ + t];
        else if (c == 80) val = 1.0f;
        else              val = 0.0f;
        v[e] = (bf16)val;
      }
      afrag[ib][ks] = v;
    }
  }

  const int nb0 = w * 4;
  #pragma unroll
  for (int mat = 0; mat < 2; ++mat) {
    const float* W    = mat ? Wq : Wk;
    const float* bias = mat ? bq : bk;
    bf16* outp        = mat ? Qb : Kb;

    f32x4 acc[2][4];
    #pragma unroll
    for (int ib = 0; ib < 2; ++ib)
      #pragma unroll
      for (int nb = 0; nb < 4; ++nb)
        acc[ib][nb] = f32x4{0.f, 0.f, 0.f, 0.f};

    #pragma unroll
    for (int nb = 0; nb < 4; ++nb) {
      int d = (nb0 + nb) * 16 + lr;
      #pragma unroll
      for (int ks = 0; ks < 3; ++ks) {
        bf16x8 bv;
        #pragma unroll
        for (int e = 0; e < 8; ++e) {
          int c = ks * 32 + h * 8 + e;
          float val;
          if (c < 80)       val = W[d * C_ + c];
          else if (c == 80) val = bias[d];
          else              val = 0.0f;
          bv[e] = (bf16)val;
        }
        #pragma unroll
        for (int ib = 0; ib < 2; ++ib)
          acc[ib][nb] = MFMA16(afrag[ib][ks], bv, acc[ib][nb]);
      }
    }

    #pragma unroll
    for (int ib = 0; ib < 2; ++ib)
      #pragma unroll
      for (int nb = 0; nb < 4; ++nb) {
        int d = (nb0 + nb) * 16 + lr;
        #pragma unroll
        for (int r = 0; r < 4; ++r) {
          int t = t0 + ib * 16 + h * 4 + r;
          outp[(size_t)(b * T_ + t) * D_ + d] = (bf16)acc[ib][nb][r];
        }
      }
  }
}

// ---------------------------------------------------------------------------
// Kernel 2: flash attention with j-splits + batch->XCD placement.
// 1D grid, flat = b + 8*(i_tile + 32*s): under round-robin block->XCD
// dispatch, all blocks of batch b land on XCD b, so K/Q/xbf (2.33 MB/batch)
// stay resident in that XCD's 4MB L2 and the 32x Q re-read is an L2 hit.
// Block = 4 waves x 16 i-rows; split s covers j in [s*512,(s+1)*512).
// ---------------------------------------------------------------------------
__global__ __launch_bounds__(256, 4) void attn_kernel(
    const bf16* __restrict__ Kb,   // [B][T][D]
    const bf16* __restrict__ Qb,   // [B][T][D]
    const bf16* __restrict__ xbf,  // [B][C][T]
    float* __restrict__ Opart,     // [NS][B][C][T]
    float* __restrict__ mpart,     // [NS][B][T]
    float* __restrict__ lpart)     // [NS][B][T]
{
  constexpr int BM = 64, BN = 64, NT = T_ / BN;  // NT = 32
  constexpr int JT_PER = NT / NS;                // 8
  __shared__ bf16 qlds[BN * D_];       // 32 KB
  __shared__ bf16 plds[4][16 * BN];    // 8 KB

  const int flat = blockIdx.x;
  const int b    = flat & 7;           // batch -> XCD (round-robin heuristic)
  const int rem  = flat >> 3;
  const int i0   = (rem & 31) * BM;
  const int s    = rem >> 5;

  const int tid  = threadIdx.x;
  const int w    = tid >> 6;
  const int lane = tid & 63;
  const int h    = lane >> 4;
  const int lr   = lane & 15;

  const bf16* Kbase = Kb + (size_t)(b * T_) * D_;
  const bf16* Qbase = Qb + (size_t)(b * T_) * D_;

  // K A-frags for this wave's 16 rows
  bf16x8 kfrag[8];
  {
    const bf16* kp = Kbase + (size_t)(i0 + w * 16 + lr) * D_ + h * 8;
    #pragma unroll
    for (int ks = 0; ks < 8; ++ks)
      kfrag[ks] = *reinterpret_cast<const bf16x8*>(kp + ks * 32);
  }

  f32x4 oacc[5];
  #pragma unroll
  for (int nb = 0; nb < 5; ++nb) oacc[nb] = f32x4{0.f, 0.f, 0.f, 0.f};
  float m_run[4], l_run[4];
  #pragma unroll
  for (int r = 0; r < 4; ++r) { m_run[r] = -INFINITY; l_run[r] = 0.f; }

  uint4 stg[8];

  auto load_stage = [&](int jt) {
    const uint4* src = reinterpret_cast<const uint4*>(Qbase + (size_t)jt * BN * D_);
    #pragma unroll
    for (int q = 0; q < 8; ++q) stg[q] = src[tid + 256 * q];
  };
  auto write_stage = [&]() {
    #pragma unroll
    for (int q = 0; q < 8; ++q) {
      int f = tid + 256 * q;
      int j = f >> 5, c8 = f & 31;
      *reinterpret_cast<uint4*>(&qlds[(j << 8) + ((c8 ^ (j & 7)) << 3)]) = stg[q];
    }
  };

  const int jt0 = s * JT_PER, jt_end = jt0 + JT_PER;

  load_stage(jt0);
  write_stage();
  __syncthreads();

  for (int jt = jt0; jt < jt_end; ++jt) {
    if (jt + 1 < jt_end) load_stage(jt + 1);  // prefetch into regs

    // --- S = K Q^T (this wave: 16 i x 64 j) ---
    f32x4 sacc[4];
    #pragma unroll
    for (int jb = 0; jb < 4; ++jb) sacc[jb] = f32x4{0.f, 0.f, 0.f, 0.f};
    __builtin_amdgcn_s_setprio(1);
    #pragma unroll
    for (int jb = 0; jb < 4; ++jb) {
      const int j = lr + jb * 16;
      const int swz = (j & 7);
      #pragma unroll
      for (int ks = 0; ks < 8; ++ks) {
        bf16x8 qf = *reinterpret_cast<const bf16x8*>(
            &qlds[(j << 8) + (((h + 4 * ks) ^ swz) << 3)]);
        sacc[jb] = MFMA16(kfrag[ks], qf, sacc[jb]);
      }
    }
    __builtin_amdgcn_s_setprio(0);

    // --- online softmax over this split's j ---
    #pragma unroll
    for (int jb = 0; jb < 4; ++jb)
      #pragma unroll
      for (int r = 0; r < 4; ++r) sacc[jb][r] *= SCALE_INV;

    float p[4][4];
    float alpha[4];
    #pragma unroll
    for (int r = 0; r < 4; ++r) {
      float mx = fmaxf(fmaxf(sacc[0][r], sacc[1][r]), fmaxf(sacc[2][r], sacc[3][r]));
      mx = fmaxf(mx, __shfl_xor(mx, 1));
      mx = fmaxf(mx, __shfl_xor(mx, 2));
      mx = fmaxf(mx, __shfl_xor(mx, 4));
      mx = fmaxf(mx, __shfl_xor(mx, 8));
      float mnew = fmaxf(m_run[r], mx);
      alpha[r]  = __expf(m_run[r] - mnew);
      m_run[r]  = mnew;
      float rs = 0.f;
      #pragma unroll
      for (int jb = 0; jb < 4; ++jb) {
        p[jb][r] = __expf(sacc[jb][r] - mnew);
        rs += p[jb][r];
      }
      rs += __shfl_xor(rs, 1);
      rs += __shfl_xor(rs, 2);
      rs += __shfl_xor(rs, 4);
      rs += __shfl_xor(rs, 8);
      l_run[r] = l_run[r] * alpha[r] + rs;
    }

    #pragma unroll
    for (int nb = 0; nb < 5; ++nb)
      #pragma unroll
      for (int r = 0; r < 4; ++r) oacc[nb][r] *= alpha[r];

    // --- P -> per-wave LDS (bf16, swizzled) ---
    #pragma unroll
    for (int jb = 0; jb < 4; ++jb)
      #pragma unroll
      for (int r = 0; r < 4; ++r) {
        int row = h * 4 + r;
        int col = lr + jb * 16;
        plds[w][row * 64 + (((col >> 3) ^ (row & 7)) << 3) + (col & 7)] =
            (bf16)p[jb][r];
      }

    // --- read P as A-frags, V frags from L2, PV MFMA ---
    bf16x8 pa[2];
    #pragma unroll
    for (int ks = 0; ks < 2; ++ks) {
      pa[ks] = *reinterpret_cast<const bf16x8*>(
          &plds[w][lr * 64 + (((h + 4 * ks) ^ (lr & 7)) << 3)]);
    }
    const bf16* vbase = xbf + (size_t)b * C_ * T_ + jt * BN;
    __builtin_amdgcn_s_setprio(1);
    #pragma unroll
    for (int nb = 0; nb < 5; ++nb) {
      const int c = lr + nb * 16;
      #pragma unroll
      for (int ks = 0; ks < 2; ++ks) {
        bf16x8 vf = *reinterpret_cast<const bf16x8*>(
            &vbase[(size_t)c * T_ + h * 8 + ks * 32]);
        oacc[nb] = MFMA16(pa[ks], vf, oacc[nb]);
      }
    }
    __builtin_amdgcn_s_setprio(0);

    __syncthreads();                  // all waves done reading qlds
    if (jt + 1 < jt_end) write_stage();
    __syncthreads();                  // next tile visible
  }

  // --- epilogue: unnormalized partials ---
  float* ob = Opart + (size_t)(s * B_ + b) * C_ * T_;
  #pragma unroll
  for (int nb = 0; nb < 5; ++nb) {
    const int c = lr + nb * 16;
    #pragma unroll
    for (int r = 0; r < 4; ++r) {
      const int i = i0 + w * 16 + h * 4 + r;
      ob[(size_t)c * T_ + i] = oacc[nb][r];
    }
  }
  if (lr == 0) {
    #pragma unroll
    for (int r = 0; r < 4; ++r) {
      const int i = i0 + w * 16 + h * 4 + r;
      mpart[(size_t)(s * B_ + b) * T_ + i] = m_run[r];
      lpart[(size_t)(s * B_ + b) * T_ + i] = l_run[r];
    }
  }
}

// ---------------------------------------------------------------------------
// Kernel 3: merge splits. out[b][c][t] = sum_s O_s e^{m_s-m*} / sum_s l_s e^{m_s-m*}
// ---------------------------------------------------------------------------
__global__ __launch_bounds__(256) void merge_kernel(
    const float* __restrict__ Opart,  // [NS][B][C][T]
    const float* __restrict__ mpart,  // [NS][B][T]
    const float* __restrict__ lpart,  // [NS][B][T]
    float* __restrict__ out)          // [B][C][T]
{
  const int b    = blockIdx.y;
  const int tid  = threadIdx.x;
  const int w    = tid >> 6;
  const int lane = tid & 63;
  const int t    = blockIdx.x * 64 + lane;

  float m[NS];
  float mmax = -INFINITY;
  #pragma unroll
  for (int s2 = 0; s2 < NS; ++s2) {
    m[s2] = mpart[(size_t)(s2 * B_ + b) * T_ + t];
    mmax = fmaxf(mmax, m[s2]);
  }
  float e[NS];
  float lsum = 0.f;
  #pragma unroll
  for (int s2 = 0; s2 < NS; ++s2) {
    e[s2] = __expf(m[s2] - mmax);
    lsum += e[s2] * lpart[(size_t)(s2 * B_ + b) * T_ + t];
  }
  const float inv = 1.0f / lsum;

  const int c0 = w * 20;
  for (int c = c0; c < c0 + 20; ++c) {
    float acc = 0.f;
    #pragma unroll
    for (int s2 = 0; s2 < NS; ++s2)
      acc += Opart[((size_t)(s2 * B_ + b) * C_ + c) * T_ + t] * e[s2];
    out[((size_t)b * C_ + c) * T_ + t] = acc * inv;
  }
}

// ---------------------------------------------------------------------------
extern "C" void kernel_launch(void* const* d_in, const int* in_sizes, int n_in,
                              void* d_out, int out_size, void* d_ws, size_t ws_size,
                              hipStream_t stream) {
  (void)in_sizes; (void)n_in; (void)out_size; (void)ws_size;
  const float* x  = (const float*)d_in[0];
  const float* Wk = (const float*)d_in[1];
  const float* bk = (const float*)d_in[2];
  const float* Wq = (const float*)d_in[3];
  const float* bq = (const float*)d_in[4];
  float* out = (float*)d_out;

  char* ws = (char*)d_ws;
  const size_t MB = 1024 * 1024;
  bf16*  Kb    = (bf16*)(ws);                 // 8 MB
  bf16*  Qb    = (bf16*)(ws + 8 * MB);        // 8 MB
  bf16*  xbf   = (bf16*)(ws + 16 * MB);       // 2.625 MB
  float* Opart = (float*)(ws + 19 * MB);      // NS*8*80*2048*4 = 20.97 MB
  float* mpart = (float*)(ws + 41 * MB);      // 256 KB
  float* lpart = (float*)(ws + 42 * MB);      // 256 KB

  dim3 blk(256);
  dim3 g1(T_ / 32, B_);
  proj_kernel<<<g1, blk, 0, stream>>>(x, Wk, bk, Wq, bq, Kb, Qb, xbf);
  attn_kernel<<<dim3(T_ / 64 * NS * B_), blk, 0, stream>>>(Kb, Qb, xbf, Opart, mpart, lpart);
  dim3 g3(T_ / 64, B_);
  merge_kernel<<<g3, blk, 0, stream>>>(Opart, mpart, lpart, out);
}

// Round 4
// 114.317 us; speedup vs baseline: 2.1700x; 1.2174x over previous
//
#include <hip/hip_runtime.h>
#include <hip/hip_bf16.h>
#include <math.h>

typedef __bf16 bf16;
typedef __bf16 bf16x8 __attribute__((ext_vector_type(8)));
typedef float  f32x4  __attribute__((ext_vector_type(4)));

#define MFMA16(a, b, c) __builtin_amdgcn_mfma_f32_16x16x32_bf16((a), (b), (c), 0, 0, 0)

typedef const uint32_t __attribute__((address_space(1)))* gq_t;
typedef uint32_t __attribute__((address_space(3)))* lq_t;

constexpr int B_ = 8, C_ = 80, T_ = 2048, D_ = 256;
constexpr int NS = 4;                       // j-splits (flash-decode style)
constexpr float SCALE_INV = 1.0f / 16.0f;   // 1/sqrt(256)

// ---------------------------------------------------------------------------
// Kernel 1: projection. K = xt @ Wk^T + bk, Q = xt @ Wq^T + bq (bf16 out),
// plus bf16 conversion of x (kept in [B][C][T] layout = V^T for the PV step).
// Bias folded in by padding C 80->96 with xt[:,80]=1, W[:,80]=bias.
// ---------------------------------------------------------------------------
__global__ __launch_bounds__(256) void proj_kernel(
    const float* __restrict__ x,   // [B][C][T]
    const float* __restrict__ Wk,  // [D][C]
    const float* __restrict__ bk,  // [D]
    const float* __restrict__ Wq,  // [D][C]
    const float* __restrict__ bq,  // [D]
    bf16* __restrict__ Kb,         // [B][T][D]
    bf16* __restrict__ Qb,         // [B][T][D]
    bf16* __restrict__ xbf)        // [B][C][T]
{
  const int t0   = blockIdx.x * 32;
  const int b    = blockIdx.y;
  const int tid  = threadIdx.x;
  const int w    = tid >> 6;
  const int lane = tid & 63;
  const int h    = lane >> 4;   // 0..3
  const int lr   = lane & 15;   // 0..15

  const float* xb = x + (size_t)b * C_ * T_;

  // bf16-convert this block's x slice
  {
    bf16* ob = xbf + (size_t)b * C_ * T_;
    #pragma unroll
    for (int q = 0; q < 10; ++q) {
      int idx = q * 256 + tid;
      int c = idx >> 5, tt = idx & 31;
      ob[c * T_ + t0 + tt] = (bf16)xb[c * T_ + t0 + tt];
    }
  }

  // A-fragments: xt rows t0..t0+31, c padded to 96
  bf16x8 afrag[2][3];
  #pragma unroll
  for (int ib = 0; ib < 2; ++ib) {
    int t = t0 + ib * 16 + lr;
    #pragma unroll
    for (int ks = 0; ks < 3; ++ks) {
      bf16x8 v;
      #pragma unroll
      for (int e = 0; e < 8; ++e) {
        int c = ks * 32 + h * 8 + e;
        float val;
        if (c < 80)       val = xb[c * T_ + t];
        else if (c == 80) val = 1.0f;
        else              val = 0.0f;
        v[e] = (bf16)val;
      }
      afrag[ib][ks] = v;
    }
  }

  const int nb0 = w * 4;
  #pragma unroll
  for (int mat = 0; mat < 2; ++mat) {
    const float* W    = mat ? Wq : Wk;
    const float* bias = mat ? bq : bk;
    bf16* outp        = mat ? Qb : Kb;

    f32x4 acc[2][4];
    #pragma unroll
    for (int ib = 0; ib < 2; ++ib)
      #pragma unroll
      for (int nb = 0; nb < 4; ++nb)
        acc[ib][nb] = f32x4{0.f, 0.f, 0.f, 0.f};

    #pragma unroll
    for (int nb = 0; nb < 4; ++nb) {
      int d = (nb0 + nb) * 16 + lr;
      #pragma unroll
      for (int ks = 0; ks < 3; ++ks) {
        bf16x8 bv;
        #pragma unroll
        for (int e = 0; e < 8; ++e) {
          int c = ks * 32 + h * 8 + e;
          float val;
          if (c < 80)       val = W[d * C_ + c];
          else if (c == 80) val = bias[d];
          else              val = 0.0f;
          bv[e] = (bf16)val;
        }
        #pragma unroll
        for (int ib = 0; ib < 2; ++ib)
          acc[ib][nb] = MFMA16(afrag[ib][ks], bv, acc[ib][nb]);
      }
    }

    #pragma unroll
    for (int ib = 0; ib < 2; ++ib)
      #pragma unroll
      for (int nb = 0; nb < 4; ++nb) {
        int d = (nb0 + nb) * 16 + lr;
        #pragma unroll
        for (int r = 0; r < 4; ++r) {
          int t = t0 + ib * 16 + h * 4 + r;
          outp[(size_t)(b * T_ + t) * D_ + d] = (bf16)acc[ib][nb][r];
        }
      }
  }
}

// ---------------------------------------------------------------------------
// Kernel 2: flash attention with j-splits + batch->XCD placement.
// Q staged via global_load_lds (zero VGPR cost): LDS dest is linear per-wave,
// the XOR swizzle is applied to the per-lane GLOBAL source address (m173
// pattern), so LDS slot (j,c8') holds Q[j][c8'^(j&7)] and the swizzled
// reader is unchanged. launch_bounds(256,3): 170-reg budget, no spill.
// ---------------------------------------------------------------------------
__global__ __launch_bounds__(256, 3) void attn_kernel(
    const bf16* __restrict__ Kb,   // [B][T][D]
    const bf16* __restrict__ Qb,   // [B][T][D]
    const bf16* __restrict__ xbf,  // [B][C][T]
    float* __restrict__ Opart,     // [NS][B][C][T]
    float* __restrict__ mpart,     // [NS][B][T]
    float* __restrict__ lpart)     // [NS][B][T]
{
  constexpr int BM = 64, BN = 64, NT = T_ / BN;  // NT = 32
  constexpr int JT_PER = NT / NS;                // 8
  __shared__ bf16 qlds[BN * D_];       // 32 KB
  __shared__ bf16 plds[4][16 * BN];    // 8 KB

  const int flat = blockIdx.x;
  const int b    = flat & 7;           // batch -> XCD (round-robin heuristic)
  const int rem  = flat >> 3;
  const int i0   = (rem & 31) * BM;
  const int s    = rem >> 5;

  const int tid  = threadIdx.x;
  const int w    = tid >> 6;
  const int lane = tid & 63;
  const int h    = lane >> 4;
  const int lr   = lane & 15;

  const bf16* Kbase = Kb + (size_t)(b * T_) * D_;
  const bf16* Qbase = Qb + (size_t)(b * T_) * D_;

  // K A-frags for this wave's 16 rows
  bf16x8 kfrag[8];
  {
    const bf16* kp = Kbase + (size_t)(i0 + w * 16 + lr) * D_ + h * 8;
    #pragma unroll
    for (int ks = 0; ks < 8; ++ks)
      kfrag[ks] = *reinterpret_cast<const bf16x8*>(kp + ks * 32);
  }

  f32x4 oacc[5];
  #pragma unroll
  for (int nb = 0; nb < 5; ++nb) oacc[nb] = f32x4{0.f, 0.f, 0.f, 0.f};
  float m_run[4], l_run[4];
  #pragma unroll
  for (int r = 0; r < 4; ++r) { m_run[r] = -INFINITY; l_run[r] = 0.f; }

  // Q tile -> LDS, direct-to-LDS with pre-swizzled global source.
  // chunk f = tid + 256q: j = f>>5, c8' = f&31;
  //   LDS (linear): elem f*8 = (q<<11) + (w<<9) + lane*8  (HW adds lane*16B)
  //   global src: Q[jt*64 + j][(c8' ^ (j&7))*8]
  auto issue_stage = [&](int jt) {
    #pragma unroll
    for (int q = 0; q < 8; ++q) {
      int f = tid + 256 * q;
      int j = f >> 5, c8 = f & 31;
      const bf16* src = Qbase + (size_t)(jt * BN + j) * D_ + ((c8 ^ (j & 7)) << 3);
      __builtin_amdgcn_global_load_lds((gq_t)src, (lq_t)&qlds[(q << 11) + (w << 9)],
                                       16, 0, 0);
    }
  };

  const int jt0 = s * JT_PER, jt_end = jt0 + JT_PER;

  issue_stage(jt0);
  asm volatile("s_waitcnt vmcnt(0)" ::: "memory");
  __syncthreads();

  for (int jt = jt0; jt < jt_end; ++jt) {
    // --- S = K Q^T (this wave: 16 i x 64 j) ---
    f32x4 sacc[4];
    #pragma unroll
    for (int jb = 0; jb < 4; ++jb) sacc[jb] = f32x4{0.f, 0.f, 0.f, 0.f};
    __builtin_amdgcn_s_setprio(1);
    #pragma unroll
    for (int jb = 0; jb < 4; ++jb) {
      const int j = lr + jb * 16;
      const int swz = (j & 7);
      #pragma unroll
      for (int ks = 0; ks < 8; ++ks) {
        bf16x8 qf = *reinterpret_cast<const bf16x8*>(
            &qlds[(j << 8) + (((h + 4 * ks) ^ swz) << 3)]);
        sacc[jb] = MFMA16(kfrag[ks], qf, sacc[jb]);
      }
    }
    __builtin_amdgcn_s_setprio(0);

    __syncthreads();                        // all waves done reading qlds
    if (jt + 1 < jt_end) issue_stage(jt + 1);  // stream next tile global->LDS

    // --- online softmax over this split's j ---
    #pragma unroll
    for (int jb = 0; jb < 4; ++jb)
      #pragma unroll
      for (int r = 0; r < 4; ++r) sacc[jb][r] *= SCALE_INV;

    float p[4][4];
    float alpha[4];
    #pragma unroll
    for (int r = 0; r < 4; ++r) {
      float mx = fmaxf(fmaxf(sacc[0][r], sacc[1][r]), fmaxf(sacc[2][r], sacc[3][r]));
      mx = fmaxf(mx, __shfl_xor(mx, 1));
      mx = fmaxf(mx, __shfl_xor(mx, 2));
      mx = fmaxf(mx, __shfl_xor(mx, 4));
      mx = fmaxf(mx, __shfl_xor(mx, 8));
      float mnew = fmaxf(m_run[r], mx);
      alpha[r]  = __expf(m_run[r] - mnew);
      m_run[r]  = mnew;
      float rs = 0.f;
      #pragma unroll
      for (int jb = 0; jb < 4; ++jb) {
        p[jb][r] = __expf(sacc[jb][r] - mnew);
        rs += p[jb][r];
      }
      rs += __shfl_xor(rs, 1);
      rs += __shfl_xor(rs, 2);
      rs += __shfl_xor(rs, 4);
      rs += __shfl_xor(rs, 8);
      l_run[r] = l_run[r] * alpha[r] + rs;
    }

    #pragma unroll
    for (int nb = 0; nb < 5; ++nb)
      #pragma unroll
      for (int r = 0; r < 4; ++r) oacc[nb][r] *= alpha[r];

    // --- P -> per-wave LDS (bf16, swizzled) ---
    #pragma unroll
    for (int jb = 0; jb < 4; ++jb)
      #pragma unroll
      for (int r = 0; r < 4; ++r) {
        int row = h * 4 + r;
        int col = lr + jb * 16;
        plds[w][row * 64 + (((col >> 3) ^ (row & 7)) << 3) + (col & 7)] =
            (bf16)p[jb][r];
      }

    // --- read P as A-frags, V frags from L2, PV MFMA ---
    bf16x8 pa[2];
    #pragma unroll
    for (int ks = 0; ks < 2; ++ks) {
      pa[ks] = *reinterpret_cast<const bf16x8*>(
          &plds[w][lr * 64 + (((h + 4 * ks) ^ (lr & 7)) << 3)]);
    }
    const bf16* vbase = xbf + (size_t)b * C_ * T_ + jt * BN;
    __builtin_amdgcn_s_setprio(1);
    #pragma unroll
    for (int nb = 0; nb < 5; ++nb) {
      const int c = lr + nb * 16;
      #pragma unroll
      for (int ks = 0; ks < 2; ++ks) {
        bf16x8 vf = *reinterpret_cast<const bf16x8*>(
            &vbase[(size_t)c * T_ + h * 8 + ks * 32]);
        oacc[nb] = MFMA16(pa[ks], vf, oacc[nb]);
      }
    }
    __builtin_amdgcn_s_setprio(0);

    // drain own Q loads (V loads already consumed), then block-wide barrier
    asm volatile("s_waitcnt vmcnt(0)" ::: "memory");
    __syncthreads();
  }

  // --- epilogue: unnormalized partials ---
  float* ob = Opart + (size_t)(s * B_ + b) * C_ * T_;
  #pragma unroll
  for (int nb = 0; nb < 5; ++nb) {
    const int c = lr + nb * 16;
    #pragma unroll
    for (int r = 0; r < 4; ++r) {
      const int i = i0 + w * 16 + h * 4 + r;
      ob[(size_t)c * T_ + i] = oacc[nb][r];
    }
  }
  if (lr == 0) {
    #pragma unroll
    for (int r = 0; r < 4; ++r) {
      const int i = i0 + w * 16 + h * 4 + r;
      mpart[(size_t)(s * B_ + b) * T_ + i] = m_run[r];
      lpart[(size_t)(s * B_ + b) * T_ + i] = l_run[r];
    }
  }
}

// ---------------------------------------------------------------------------
// Kernel 3: merge splits. out[b][c][t] = sum_s O_s e^{m_s-m*} / sum_s l_s e^{m_s-m*}
// ---------------------------------------------------------------------------
__global__ __launch_bounds__(256) void merge_kernel(
    const float* __restrict__ Opart,  // [NS][B][C][T]
    const float* __restrict__ mpart,  // [NS][B][T]
    const float* __restrict__ lpart,  // [NS][B][T]
    float* __restrict__ out)          // [B][C][T]
{
  const int b    = blockIdx.y;
  const int tid  = threadIdx.x;
  const int w    = tid >> 6;
  const int lane = tid & 63;
  const int t    = blockIdx.x * 64 + lane;

  float m[NS];
  float mmax = -INFINITY;
  #pragma unroll
  for (int s2 = 0; s2 < NS; ++s2) {
    m[s2] = mpart[(size_t)(s2 * B_ + b) * T_ + t];
    mmax = fmaxf(mmax, m[s2]);
  }
  float e[NS];
  float lsum = 0.f;
  #pragma unroll
  for (int s2 = 0; s2 < NS; ++s2) {
    e[s2] = __expf(m[s2] - mmax);
    lsum += e[s2] * lpart[(size_t)(s2 * B_ + b) * T_ + t];
  }
  const float inv = 1.0f / lsum;

  const int c0 = w * 20;
  for (int c = c0; c < c0 + 20; ++c) {
    float acc = 0.f;
    #pragma unroll
    for (int s2 = 0; s2 < NS; ++s2)
      acc += Opart[((size_t)(s2 * B_ + b) * C_ + c) * T_ + t] * e[s2];
    out[((size_t)b * C_ + c) * T_ + t] = acc * inv;
  }
}

// ---------------------------------------------------------------------------
extern "C" void kernel_launch(void* const* d_in, const int* in_sizes, int n_in,
                              void* d_out, int out_size, void* d_ws, size_t ws_size,
                              hipStream_t stream) {
  (void)in_sizes; (void)n_in; (void)out_size; (void)ws_size;
  const float* x  = (const float*)d_in[0];
  const float* Wk = (const float*)d_in[1];
  const float* bk = (const float*)d_in[2];
  const float* Wq = (const float*)d_in[3];
  const float* bq = (const float*)d_in[4];
  float* out = (float*)d_out;

  char* ws = (char*)d_ws;
  const size_t MB = 1024 * 1024;
  bf16*  Kb    = (bf16*)(ws);                 // 8 MB
  bf16*  Qb    = (bf16*)(ws + 8 * MB);        // 8 MB
  bf16*  xbf   = (bf16*)(ws + 16 * MB);       // 2.625 MB
  float* Opart = (float*)(ws + 19 * MB);      // NS*8*80*2048*4 = 20.97 MB
  float* mpart = (float*)(ws + 41 * MB);      // 256 KB
  float* lpart = (float*)(ws + 42 * MB);      // 256 KB

  dim3 blk(256);
  dim3 g1(T_ / 32, B_);
  proj_kernel<<<g1, blk, 0, stream>>>(x, Wk, bk, Wq, bq, Kb, Qb, xbf);
  attn_kernel<<<dim3(T_ / 64 * NS * B_), blk, 0, stream>>>(Kb, Qb, xbf, Opart, mpart, lpart);
  dim3 g3(T_ / 64, B_);
  merge_kernel<<<g3, blk, 0, stream>>>(Opart, mpart, lpart, out);
}